// Round 9
// baseline (119.028 us; speedup 1.0000x reference)
//
#include <hip/hip_runtime.h>
#include <hip/hip_bf16.h>

typedef __attribute__((ext_vector_type(8))) short short8_t;
typedef __attribute__((ext_vector_type(4))) float f32x4;

#define BATCH 16
#define CIN   512
#define COUT  512
#define TT    4096

// pack 2 f32 -> u32 of 2 bf16 (RNE); pairs into v_cvt_pk_bf16_f32
__device__ __forceinline__ uint pk2(float a, float b) {
    ushort lo = __builtin_bit_cast(ushort, __float2bfloat16(a));
    ushort hi = __builtin_bit_cast(ushort, __float2bfloat16(b));
    return (uint)lo | ((uint)hi << 16);
}

// ---------------------------------------------------------------------------
// Pre-pass 1: W (fp32 [512][512]) -> bf16 MFMA A-fragment order (verified R5+):
//   Wb[bm][ksg][g][r][8k], bm=m>>4, r=m&15, ksg=k>>5, g=(k>>3)&3
// ---------------------------------------------------------------------------
extern "C" __global__ __launch_bounds__(256)
void wconv(const float* __restrict__ W, ushort* __restrict__ Wb)
{
    const int i  = blockIdx.x * 256 + threadIdx.x;   // [0, 65536)
    const int m  = i >> 7;
    const int k0 = (i & 127) * 4;
    const float4 v = *(const float4*)(W + (size_t)m * CIN + k0);
    const int bm = m >> 4, r = m & 15;
    const int ksg = k0 >> 5, g = (k0 >> 3) & 3, k7 = k0 & 7;
    uint2 q;
    q.x = pk2(v.x, v.y);
    q.y = pk2(v.z, v.w);
    *(uint2*)&Wb[(size_t)bm * 8192 + ksg * 512 + g * 128 + r * 8 + k7] = q;
}

// ---------------------------------------------------------------------------
// Pre-pass 2: pre (fp32 [b][k][t]) -> bf16 MFMA B-fragment order:
//   preT[b][ts][ksg][g][tt][8k], ts=t>>4, tt=t&15, ksg=k>>5, g=(k>>3)&3
// One B fragment = one coalesced dwordx4; a wave's 4 B-frags = 1 KB contig.
// Thread: 8 k x 1 t (8 strided dword reads -> 4 cvt_pk -> one 16B write).
// Wave write = 1 KB contiguous (lane = g*16+tt). BW-bound: ~192 MB traffic.
// ---------------------------------------------------------------------------
extern "C" __global__ __launch_bounds__(256)
void ptrans(const float* __restrict__ pre, ushort* __restrict__ preT)
{
    const int gt  = blockIdx.x * 256 + threadIdx.x;  // [0, 2^22)
    const int tt  = gt & 15;
    const int g   = (gt >> 4) & 3;
    const int ksg = (gt >> 6) & 15;
    const int ts  = (gt >> 10) & 255;
    const int b   = gt >> 18;

    const float* src = pre + ((size_t)b * CIN + ksg * 32 + g * 8) * TT + ts * 16 + tt;
    float v[8];
#pragma unroll
    for (int j = 0; j < 8; ++j) v[j] = src[(size_t)j * TT];

    uint4 q;
    q.x = pk2(v[0], v[1]);
    q.y = pk2(v[2], v[3]);
    q.z = pk2(v[4], v[5]);
    q.w = pk2(v[6], v[7]);
    *(uint4*)&preT[(size_t)(b * 256 + ts) * 8192 + ksg * 512 + g * 128 + tt * 8] = q;
}

// ---------------------------------------------------------------------------
// Main GEMM: NO LDS, NO barriers, NO cvt. Block 128m x 128t, 4 waves (2x2),
// wave tile 64m x 64t (mi=4, ni=4, acc=64 VGPR). Per K-step (32): 4 A-frag +
// 4 B-frag coalesced dwordx4 + 16 MFMA. 2-deep named-reg rotation.
// ---------------------------------------------------------------------------
extern "C" __global__ __launch_bounds__(256)
void gemm_frag(const ushort* __restrict__ Wb, const ushort* __restrict__ preT,
               const float* __restrict__ bias, float* __restrict__ out)
{
    const int tid  = threadIdx.x;
    const int lane = tid & 63;
    const int wv   = tid >> 6;
    const int wm   = wv >> 1, wt = wv & 1;
    const int g    = lane >> 4;
    const int l15  = lane & 15;

    // XCD-chunked swizzle: ids id..id+3 share one B-panel (same b, tb).
    const int id   = ((blockIdx.x & 7) << 8) | (blockIdx.x >> 3);
    const int mblk = id & 3;
    const int tb   = (id >> 2) & 31;
    const int bb   = id >> 7;

    const int m0 = mblk << 7;            // [0,512) step 128
    const int t0 = tb << 7;              // [0,4096) step 128

    const int bmBase = (m0 >> 4) + wm * 4;              // + mi
    const int tsBase = bb * 256 + (t0 >> 4) + wt * 4;   // + ni
    const int fo     = g * 128 + l15 * 8;               // intra-frag offset

    f32x4 acc[4][4];
#pragma unroll
    for (int i = 0; i < 4; ++i)
#pragma unroll
        for (int j = 0; j < 4; ++j) acc[i][j] = (f32x4)0.0f;

    short8_t a0[4], b0[4], a1[4], b1[4];

#define LOADF(K, A, B) do { \
    _Pragma("unroll") \
    for (int mi = 0; mi < 4; ++mi) \
        A[mi] = *(const short8_t*)(Wb + (size_t)(bmBase + mi) * 8192 + (K) * 512 + fo); \
    _Pragma("unroll") \
    for (int ni = 0; ni < 4; ++ni) \
        B[ni] = *(const short8_t*)(preT + (size_t)(tsBase + ni) * 8192 + (K) * 512 + fo); \
    } while (0)

#define MM(A, B) do { \
    _Pragma("unroll") \
    for (int mi = 0; mi < 4; ++mi) \
        _Pragma("unroll") \
        for (int ni = 0; ni < 4; ++ni) \
            acc[mi][ni] = __builtin_amdgcn_mfma_f32_16x16x32_bf16(A[mi], B[ni], acc[mi][ni], 0, 0, 0); \
    } while (0)

    LOADF(0, a0, b0);
#pragma unroll
    for (int k = 0; k < 16; ++k) {
        if ((k & 1) == 0) {
            if (k < 15) LOADF(k + 1, a1, b1);
            MM(a0, b0);
        } else {
            if (k < 15) LOADF(k + 1, a0, b0);
            MM(a1, b1);
        }
    }

    // epilogue: out = 2*(acc + bias)
    const int orow = m0 + wm * 64 + g * 4;   // + mi*16 + r
    float bv[4][4];
#pragma unroll
    for (int mi = 0; mi < 4; ++mi)
#pragma unroll
        for (int r = 0; r < 4; ++r)
            bv[mi][r] = bias[orow + mi * 16 + r];

    float* outB = out + (size_t)bb * ((size_t)COUT * TT);
#pragma unroll
    for (int mi = 0; mi < 4; ++mi) {
#pragma unroll
        for (int ni = 0; ni < 4; ++ni) {
            const int t = t0 + wt * 64 + ni * 16 + l15;
#pragma unroll
            for (int r = 0; r < 4; ++r) {
                const int o = orow + mi * 16 + r;
                outB[(size_t)o * TT + t] = 2.0f * (acc[mi][ni][r] + bv[mi][r]);
            }
        }
    }
}

// ---------------------------------------------------------------------------
// Fallback (ws too small): R8 fused kernel, inline W-cvt, known-passing.
// ---------------------------------------------------------------------------
extern "C" __global__ __launch_bounds__(256)
void gemm_fused_fb(const float* __restrict__ pre, const float* __restrict__ W,
                   const float* __restrict__ bias, float* __restrict__ out)
{
    __shared__ alignas(16) ushort LB[64 * 32 * 8];   // 32 KiB

    const int tid  = threadIdx.x;
    const int lane = tid & 63;
    const int wv   = tid >> 6;
    const int g    = lane >> 4;
    const int l15  = lane & 15;

    const int id   = ((blockIdx.x & 7) << 9) | (blockIdx.x >> 3);
    const int mblk = id & 1;
    const int ti   = (id >> 1) & 127;
    const int bb   = id >> 8;

    const int m0 = mblk << 8;
    const int t0 = ti << 5;

    const float* preB = pre + (size_t)bb * ((size_t)CIN * TT);

#pragma unroll
    for (int it = 0; it < 2; ++it) {
        const int slot = it * 256 + tid;
        const int ko   = slot >> 3;
        const int tg   = slot & 7;
        float4 v[8];
#pragma unroll
        for (int j = 0; j < 8; ++j)
            v[j] = *(const float4*)(preB + (size_t)(ko * 8 + j) * TT + t0 + tg * 4);
#pragma unroll
        for (int jj = 0; jj < 4; ++jj) {
            uint4 q;
            q.x = pk2(((const float*)&v[0])[jj], ((const float*)&v[1])[jj]);
            q.y = pk2(((const float*)&v[2])[jj], ((const float*)&v[3])[jj]);
            q.z = pk2(((const float*)&v[4])[jj], ((const float*)&v[5])[jj]);
            q.w = pk2(((const float*)&v[6])[jj], ((const float*)&v[7])[jj]);
            const int sl = (tg * 4 + jj) ^ (ko & 7);
            *(uint4*)&LB[ko * 256 + sl * 8] = q;
        }
    }
    __syncthreads();

    f32x4 acc[4][2];
#pragma unroll
    for (int i = 0; i < 4; ++i)
#pragma unroll
        for (int j = 0; j < 2; ++j) acc[i][j] = (f32x4)0.0f;

#pragma unroll 4
    for (int it = 0; it < 16; ++it) {
        short8_t af[4], bf[2];
#pragma unroll
        for (int mi = 0; mi < 4; ++mi) {
            const float* ab = W + (size_t)(m0 + wv * 64 + mi * 16 + l15) * CIN
                              + it * 32 + g * 8;
            const float4 u0 = *(const float4*)ab;
            const float4 u1 = *(const float4*)(ab + 4);
            uint4 qq;
            qq.x = pk2(u0.x, u0.y); qq.y = pk2(u0.z, u0.w);
            qq.z = pk2(u1.x, u1.y); qq.w = pk2(u1.z, u1.w);
            af[mi] = __builtin_bit_cast(short8_t, qq);
        }
#pragma unroll
        for (int ni = 0; ni < 2; ++ni) {
            const int ko = it * 4 + g;
            const int sl = (ni * 16 + l15) ^ (ko & 7);
            bf[ni] = *(const short8_t*)&LB[ko * 256 + sl * 8];
        }
#pragma unroll
        for (int mi = 0; mi < 4; ++mi)
#pragma unroll
            for (int ni = 0; ni < 2; ++ni)
                acc[mi][ni] = __builtin_amdgcn_mfma_f32_16x16x32_bf16(af[mi], bf[ni], acc[mi][ni], 0, 0, 0);
    }

    const int orow = m0 + wv * 64 + g * 4;
    float bv[4][4];
#pragma unroll
    for (int mi = 0; mi < 4; ++mi)
#pragma unroll
        for (int r = 0; r < 4; ++r)
            bv[mi][r] = bias[orow + mi * 16 + r];

    float* outB = out + (size_t)bb * ((size_t)COUT * TT);
#pragma unroll
    for (int mi = 0; mi < 4; ++mi) {
#pragma unroll
        for (int ni = 0; ni < 2; ++ni) {
            const int t = t0 + ni * 16 + l15;
#pragma unroll
            for (int r = 0; r < 4; ++r) {
                const int o = orow + mi * 16 + r;
                outB[(size_t)o * TT + t] = 2.0f * (acc[mi][ni][r] + bv[mi][r]);
            }
        }
    }
}

extern "C" void kernel_launch(void* const* d_in, const int* in_sizes, int n_in,
                              void* d_out, int out_size, void* d_ws, size_t ws_size,
                              hipStream_t stream)
{
    const float* pre  = (const float*)d_in[0];   // [16, 512, 4096] fp32
    const float* Wp   = (const float*)d_in[1];   // [512, 512] fp32
    const float* bias = (const float*)d_in[2];   // [512] fp32
    float* out = (float*)d_out;                  // [16, 512, 4096] fp32

    const size_t wb_bytes   = (size_t)COUT * CIN * sizeof(ushort);           // 512 KiB
    const size_t preT_bytes = (size_t)BATCH * CIN * TT * sizeof(ushort);     // 64 MiB

    if (ws_size >= wb_bytes + preT_bytes) {
        ushort* Wb   = (ushort*)d_ws;
        ushort* preT = (ushort*)((char*)d_ws + wb_bytes);
        hipLaunchKernelGGL(wconv,  dim3(256),   dim3(256), 0, stream, Wp, Wb);
        hipLaunchKernelGGL(ptrans, dim3(16384), dim3(256), 0, stream, pre, preT);
        hipLaunchKernelGGL(gemm_frag, dim3(2048), dim3(256), 0, stream,
                           Wb, preT, bias, out);
    } else {
        hipLaunchKernelGGL(gemm_fused_fb, dim3(BATCH * 2 * 128), dim3(256), 0, stream,
                           pre, Wp, bias, out);
    }
}

// Round 10
// 81.722 us; speedup vs baseline: 1.4565x; 1.4565x over previous
//
#include <hip/hip_runtime.h>
#include <hip/hip_bf16.h>

typedef __attribute__((ext_vector_type(8))) short short8_t;
typedef __attribute__((ext_vector_type(4))) float f32x4;

#define BATCH 16
#define CIN   512
#define COUT  512
#define TT    4096
#define BKT   32
#define NKT   16     // CIN / BKT

// pack 2 f32 -> u32 of 2 bf16 (RNE); pairs into v_cvt_pk_bf16_f32
__device__ __forceinline__ uint pk2(float a, float b) {
    ushort lo = __builtin_bit_cast(ushort, __float2bfloat16(a));
    ushort hi = __builtin_bit_cast(ushort, __float2bfloat16(b));
    return (uint)lo | ((uint)hi << 16);
}

#define SCHEDB()   __builtin_amdgcn_sched_barrier(0)
#define WAIT_VM(N) do { asm volatile("s_waitcnt vmcnt(" #N ")" ::: "memory"); SCHEDB(); } while (0)
#define WAIT_LGKM() do { asm volatile("s_waitcnt lgkmcnt(0)" ::: "memory"); SCHEDB(); } while (0)
#define RAW_BARRIER() do { __builtin_amdgcn_s_barrier(); SCHEDB(); } while (0)

// ---------------------------------------------------------------------------
// Pre-pass: W (fp32 [512][512]) -> bf16 MFMA A-fragment order (verified R5-R9):
//   Wb[bm][ksg][g][r][8k], bm=m>>4, r=m&15, ksg=k>>5, g=(k>>3)&3
// ---------------------------------------------------------------------------
extern "C" __global__ __launch_bounds__(256)
void wconv(const float* __restrict__ W, ushort* __restrict__ Wb)
{
    const int i  = blockIdx.x * 256 + threadIdx.x;   // [0, 65536)
    const int m  = i >> 7;
    const int k0 = (i & 127) * 4;
    const float4 v = *(const float4*)(W + (size_t)m * CIN + k0);
    const int bm = m >> 4, r = m & 15;
    const int ksg = k0 >> 5, g = (k0 >> 3) & 3, k7 = k0 & 7;
    uint2 q;
    q.x = pk2(v.x, v.y);
    q.y = pk2(v.z, v.w);
    *(uint2*)&Wb[(size_t)bm * 8192 + ksg * 512 + g * 128 + r * 8 + k7] = q;
}

// ---------------------------------------------------------------------------
// Fused GEMM: tile 128m x 64t, BKT=32 (16 steps), 4 waves (wave 32m x 64t).
// Pipeline (m201-style counted vmcnt, raw s_barrier):
//   iter kt: A-frags(kt) [2 dwordx4, L2 Wb] ; gload_lds tile kt+2 (fp32,
//   3-ring RAW) ; vmcnt(2) retires {A(kt), G(kt+1)}, leaves G(kt+2) in
//   flight ; lgkmcnt(0) ; s_barrier ; MFMA(kt) from bf16 BF[kt&1] ;
//   CVT(kt+1): RAW[(kt+1)%3] fp32 -> BF[(kt+1)&1] bf16 (reads each elem
//   once, b32 lane=t 2-way free; writes b128 wave-contiguous, 0-conflict).
// All fp32->bf16 cvt is on exactly-once LDS passes, one tile ahead of use.
// ---------------------------------------------------------------------------
template<bool WSB>
__global__ __launch_bounds__(256)
void conv2x1_gemm(const float* __restrict__ pre, const float* __restrict__ W,
                  const ushort* __restrict__ Wb,
                  const float* __restrict__ bias, float* __restrict__ out)
{
    __shared__ float  RAW[3][BKT * 64];      // 3 x 8 KiB fp32 ring
    __shared__ ushort BF [2][4 * 64 * 8];    // 2 x 4 KiB bf16 (granules [p][t][8k])

    const int tid  = threadIdx.x;
    const int lane = tid & 63;
    const int wv   = tid >> 6;          // wave = m-strip [0,4); also cvt k-octet
    const int g    = lane >> 4;
    const int l15  = lane & 15;

    // XCD-chunked bijective swizzle (4096 = 8*512); ids id..id+3 share a
    // B-panel (same bb, ti) on one XCD's L2.
    const int id   = ((blockIdx.x & 7) << 9) | (blockIdx.x >> 3);
    const int mblk = id & 3;
    const int ti   = (id >> 2) & 63;
    const int bb   = id >> 8;

    const int m0 = mblk << 7;   // [0,512) step 128
    const int t0 = ti << 6;     // [0,4096) step 64

    const float* preB   = pre + (size_t)bb * ((size_t)CIN * TT);
    const int    bmBase = (m0 >> 4) + wv * 2;

    f32x4 acc[2][4];
#pragma unroll
    for (int i = 0; i < 2; ++i)
#pragma unroll
        for (int j = 0; j < 4; ++j) acc[i][j] = (f32x4)0.0f;

    // ---- B stage: 2 gload_lds (16B) per thread; RAW[slot] is linear [k][t] ----
#define STAGE(J) do { \
    _Pragma("unroll") \
    for (int i = 0; i < 2; ++i) { \
        const int krow = wv*8 + i*4 + (lane >> 4); \
        const float* gsrc = preB + (size_t)((J)*BKT + krow) * TT + t0 + ((lane & 15) << 2); \
        float* ldst = &RAW[(J) % 3][(wv*128 + i*64 + lane) * 4]; \
        __builtin_amdgcn_global_load_lds((const __attribute__((address_space(1))) void*)gsrc, \
                                         (__attribute__((address_space(3))) void*)ldst, 16, 0, 0); \
    } } while (0)

    // ---- A fragments for step KT (one ksg per step since BKT=32) ----
#define LOAD_A(KT, AF) do { \
    if constexpr (WSB) { \
        _Pragma("unroll") \
        for (int mi = 0; mi < 2; ++mi) \
            AF[mi] = *(const short8_t*)(Wb + (size_t)(bmBase + mi) * 8192 \
                                        + (KT) * 512 + g * 128 + l15 * 8); \
    } else { \
        _Pragma("unroll") \
        for (int mi = 0; mi < 2; ++mi) { \
            const float* ab = W + (size_t)(m0 + wv*32 + mi*16 + l15) * CIN + (KT)*BKT + g*8; \
            const float4 u0 = *(const float4*)ab; \
            const float4 u1 = *(const float4*)(ab + 4); \
            uint4 qq; \
            qq.x = pk2(u0.x, u0.y); qq.y = pk2(u0.z, u0.w); \
            qq.z = pk2(u1.x, u1.y); qq.w = pk2(u1.z, u1.w); \
            AF[mi] = __builtin_bit_cast(short8_t, qq); \
        } \
    } } while (0)

    // ---- cvt tile J: RAW[J%3] fp32 [k][t] -> BF[J&1] granules [p][t][8k] ----
    // thread: t = tid&63, k-octet p = wv. reads: 8 x b32 (banks=lane%32, 2-way
    // free). write: one b128, wave covers 1 KB contiguous (conflict-free).
#define CVT(J) do { \
    const int ct = tid & 63; \
    float f[8]; \
    _Pragma("unroll") \
    for (int j = 0; j < 8; ++j) \
        f[j] = RAW[(J) % 3][(wv*8 + j) * 64 + ct]; \
    uint4 q; \
    q.x = pk2(f[0], f[1]); \
    q.y = pk2(f[2], f[3]); \
    q.z = pk2(f[4], f[5]); \
    q.w = pk2(f[6], f[7]); \
    *(uint4*)&BF[(J) & 1][wv * 512 + ct * 8] = q; \
    } while (0)

    // ---- MFMA step: 4 b128 frag reads (16-lane contiguous 256B) + 8 MFMA ----
#define MFMA_STEP(J, AF) do { \
    short8_t bf[4]; \
    _Pragma("unroll") \
    for (int ni = 0; ni < 4; ++ni) \
        bf[ni] = *(const short8_t*)&BF[(J) & 1][g * 512 + (ni*16 + l15) * 8]; \
    _Pragma("unroll") \
    for (int mi = 0; mi < 2; ++mi) \
        _Pragma("unroll") \
        for (int ni = 0; ni < 4; ++ni) \
            acc[mi][ni] = __builtin_amdgcn_mfma_f32_16x16x32_bf16(AF[mi], bf[ni], acc[mi][ni], 0, 0, 0); \
    } while (0)

    // -------- prologue --------
    STAGE(0);                 // G(0)
    STAGE(1);                 // G(1)
    WAIT_VM(2);               // retire G(0); G(1) stays in flight
    RAW_BARRIER();            // all waves' G(0) landed
    CVT(0);                   // RAW[0] -> BF[0]

    // -------- main loop --------
#pragma unroll
    for (int kt = 0; kt < NKT; ++kt) {
        short8_t af[2];
        LOAD_A(kt, af);                   // older than G(kt+2) in vmcnt FIFO
        if (kt + 2 < NKT) {
            STAGE(kt + 2);
            WAIT_VM(2);                   // retire {G(kt+1), A(kt)}; G(kt+2) in flight
        } else {
            WAIT_VM(0);                   // tail: drain everything
        }
        WAIT_LGKM();                      // CVT(kt) writes / prior ds ops retired
        RAW_BARRIER();                    // BF[kt&1] + RAW[(kt+1)%3] visible
        MFMA_STEP(kt, af);
        if (kt + 1 < NKT) CVT(kt + 1);
    }

    // -------- epilogue: out = 2*(acc + bias) --------
    const int orow = m0 + wv*32 + g*4;     // + mi*16 + r
    float bv[2][4];
#pragma unroll
    for (int mi = 0; mi < 2; ++mi)
#pragma unroll
        for (int r = 0; r < 4; ++r)
            bv[mi][r] = bias[orow + mi*16 + r];

    float* outB = out + (size_t)bb * ((size_t)COUT * TT);
#pragma unroll
    for (int mi = 0; mi < 2; ++mi) {
#pragma unroll
        for (int ni = 0; ni < 4; ++ni) {
            const int t = t0 + ni*16 + l15;
#pragma unroll
            for (int r = 0; r < 4; ++r) {
                const int o = orow + mi*16 + r;
                outB[(size_t)o * TT + t] = 2.0f * (acc[mi][ni][r] + bv[mi][r]);
            }
        }
    }
}

extern "C" void kernel_launch(void* const* d_in, const int* in_sizes, int n_in,
                              void* d_out, int out_size, void* d_ws, size_t ws_size,
                              hipStream_t stream)
{
    const float* pre  = (const float*)d_in[0];   // [16, 512, 4096] fp32
    const float* Wp   = (const float*)d_in[1];   // [512, 512] fp32
    const float* bias = (const float*)d_in[2];   // [512] fp32
    float* out = (float*)d_out;                  // [16, 512, 4096] fp32

    const size_t wb_bytes = (size_t)COUT * CIN * sizeof(ushort);   // 512 KiB

    const dim3 grid(BATCH * 4 * 64);   // 16 b x 4 m-tiles x 64 t-tiles = 4096
    const dim3 block(256);

    if (ws_size >= wb_bytes) {
        ushort* Wb = (ushort*)d_ws;
        hipLaunchKernelGGL(wconv, dim3(256), dim3(256), 0, stream, Wp, Wb);
        hipLaunchKernelGGL((conv2x1_gemm<true>), grid, block, 0, stream,
                           pre, Wp, Wb, bias, out);
    } else {
        hipLaunchKernelGGL((conv2x1_gemm<false>), grid, block, 0, stream,
                           pre, Wp, (const ushort*)nullptr, bias, out);
    }
}

// Round 11
// 72.279 us; speedup vs baseline: 1.6468x; 1.1306x over previous
//
#include <hip/hip_runtime.h>
#include <hip/hip_bf16.h>

typedef __attribute__((ext_vector_type(8))) short short8_t;
typedef __attribute__((ext_vector_type(4))) float f32x4;

#define BATCH 16
#define CIN   512
#define COUT  512
#define TT    4096
#define BKT   32
#define NKT   16     // CIN / BKT

// pack 2 f32 -> u32 of 2 bf16 (RNE); pairs into v_cvt_pk_bf16_f32
__device__ __forceinline__ uint pk2(float a, float b) {
    ushort lo = __builtin_bit_cast(ushort, __float2bfloat16(a));
    ushort hi = __builtin_bit_cast(ushort, __float2bfloat16(b));
    return (uint)lo | ((uint)hi << 16);
}

#define SCHEDB()   __builtin_amdgcn_sched_barrier(0)
#define WAIT_VM(N) do { asm volatile("s_waitcnt vmcnt(" #N ")" ::: "memory"); SCHEDB(); } while (0)
#define WAIT_LGKM() do { asm volatile("s_waitcnt lgkmcnt(0)" ::: "memory"); SCHEDB(); } while (0)
#define RAW_BARRIER() do { __builtin_amdgcn_s_barrier(); SCHEDB(); } while (0)

// ---------------------------------------------------------------------------
// Pre-pass: W (fp32 [512][512]) -> bf16 MFMA A-fragment order (verified R5-R10):
//   Wb[bm][ksg][g][r][8k], bm=m>>4, r=m&15, ksg=k>>5, g=(k>>3)&3
// ---------------------------------------------------------------------------
extern "C" __global__ __launch_bounds__(256)
void wconv(const float* __restrict__ W, ushort* __restrict__ Wb)
{
    const int i  = blockIdx.x * 256 + threadIdx.x;   // [0, 65536)
    const int m  = i >> 7;
    const int k0 = (i & 127) * 4;
    const float4 v = *(const float4*)(W + (size_t)m * CIN + k0);
    const int bm = m >> 4, r = m & 15;
    const int ksg = k0 >> 5, g = (k0 >> 3) & 3, k7 = k0 & 7;
    uint2 q;
    q.x = pk2(v.x, v.y);
    q.y = pk2(v.z, v.w);
    *(uint2*)&Wb[(size_t)bm * 8192 + ksg * 512 + g * 128 + r * 8 + k7] = q;
}

// ---------------------------------------------------------------------------
// Fused GEMM: tile 256m x 64t, BKT=32 (16 steps), 4 waves (wave 64m x 64t,
// 16 MFMA/wave/step). B-pipeline identical to R10 (verified 0-conflict):
//   gload_lds fp32 -> RAW 3-ring ; CVT one tile ahead -> BF bf16 2-ring ;
//   counted vmcnt + raw s_barrier keep G(kt+2) in flight across barriers.
// New vs R10: A-frags prefetched ONE ITER AHEAD (afA/afB rotation) so the
// Wb L2 latency overlaps MFMA(kt)+CVT(kt+1). Steady-state vmcnt(6) retires
// exactly {A(kt), G(kt+1)}.
// ---------------------------------------------------------------------------
template<bool WSB>
__global__ __launch_bounds__(256)
void conv2x1_gemm(const float* __restrict__ pre, const float* __restrict__ W,
                  const ushort* __restrict__ Wb,
                  const float* __restrict__ bias, float* __restrict__ out)
{
    __shared__ float  RAW[3][BKT * 64];      // 3 x 8 KiB fp32 ring
    __shared__ ushort BF [2][4 * 64 * 8];    // 2 x 4 KiB bf16 (granules [p][t][8k])

    const int tid  = threadIdx.x;
    const int lane = tid & 63;
    const int wv   = tid >> 6;          // wave = 64m strip [0,4); also cvt k-octet
    const int g    = lane >> 4;
    const int l15  = lane & 15;

    // XCD-chunked bijective swizzle (2048 = 8*256); consecutive ids share a
    // B-panel (same bb, ti) on one XCD's L2.
    const int id   = ((blockIdx.x & 7) << 8) | (blockIdx.x >> 3);
    const int mblk = id & 1;
    const int ti   = (id >> 1) & 63;
    const int bb   = id >> 7;

    const int m0 = mblk << 8;   // {0, 256}
    const int t0 = ti << 6;     // [0,4096) step 64

    const float* preB   = pre + (size_t)bb * ((size_t)CIN * TT);
    const int    bmBase = (m0 >> 4) + wv * 4;

    f32x4 acc[4][4];
#pragma unroll
    for (int i = 0; i < 4; ++i)
#pragma unroll
        for (int j = 0; j < 4; ++j) acc[i][j] = (f32x4)0.0f;

    short8_t afA[4], afB[4];

    // ---- B stage: 2 gload_lds (16B) per thread; RAW[slot] is linear [k][t] ----
#define STAGE(J) do { \
    _Pragma("unroll") \
    for (int i = 0; i < 2; ++i) { \
        const int krow = wv*8 + i*4 + (lane >> 4); \
        const float* gsrc = preB + (size_t)((J)*BKT + krow) * TT + t0 + ((lane & 15) << 2); \
        float* ldst = &RAW[(J) % 3][(wv*128 + i*64 + lane) * 4]; \
        __builtin_amdgcn_global_load_lds((const __attribute__((address_space(1))) void*)gsrc, \
                                         (__attribute__((address_space(3))) void*)ldst, 16, 0, 0); \
    } } while (0)

    // ---- A fragments for step KT (one ksg per step since BKT=32) ----
#define LOAD_A(KT, AF) do { \
    if constexpr (WSB) { \
        _Pragma("unroll") \
        for (int mi = 0; mi < 4; ++mi) \
            AF[mi] = *(const short8_t*)(Wb + (size_t)(bmBase + mi) * 8192 \
                                        + (KT) * 512 + g * 128 + l15 * 8); \
    } else { \
        _Pragma("unroll") \
        for (int mi = 0; mi < 4; ++mi) { \
            const float* ab = W + (size_t)(m0 + wv*64 + mi*16 + l15) * CIN + (KT)*BKT + g*8; \
            const float4 u0 = *(const float4*)ab; \
            const float4 u1 = *(const float4*)(ab + 4); \
            uint4 qq; \
            qq.x = pk2(u0.x, u0.y); qq.y = pk2(u0.z, u0.w); \
            qq.z = pk2(u1.x, u1.y); qq.w = pk2(u1.z, u1.w); \
            AF[mi] = __builtin_bit_cast(short8_t, qq); \
        } \
    } } while (0)

    // ---- cvt tile J: RAW[J%3] fp32 [k][t] -> BF[J&1] granules [p][t][8k] ----
    // thread: t = tid&63, k-octet p = wv. reads: 8 x b32 (2-way, free).
    // write: one b128, wave covers 1 KB contiguous (conflict-free). (R10 ✓)
#define CVT(J) do { \
    const int ct = tid & 63; \
    float f[8]; \
    _Pragma("unroll") \
    for (int j = 0; j < 8; ++j) \
        f[j] = RAW[(J) % 3][(wv*8 + j) * 64 + ct]; \
    uint4 q; \
    q.x = pk2(f[0], f[1]); \
    q.y = pk2(f[2], f[3]); \
    q.z = pk2(f[4], f[5]); \
    q.w = pk2(f[6], f[7]); \
    *(uint4*)&BF[(J) & 1][wv * 512 + ct * 8] = q; \
    } while (0)

    // ---- MFMA step: 4 b128 frag reads (16-lane contiguous 256B) + 16 MFMA ----
#define MFMA_STEP(J, AF) do { \
    short8_t bf[4]; \
    _Pragma("unroll") \
    for (int ni = 0; ni < 4; ++ni) \
        bf[ni] = *(const short8_t*)&BF[(J) & 1][g * 512 + (ni*16 + l15) * 8]; \
    _Pragma("unroll") \
    for (int mi = 0; mi < 4; ++mi) \
        _Pragma("unroll") \
        for (int ni = 0; ni < 4; ++ni) \
            acc[mi][ni] = __builtin_amdgcn_mfma_f32_16x16x32_bf16(AF[mi], bf[ni], acc[mi][ni], 0, 0, 0); \
    } while (0)

    // -------- prologue --------
    STAGE(0);                 // G(0): 2 loads
    STAGE(1);                 // G(1): 2 loads
    LOAD_A(0, afA);           // A(0): 4 loads
    WAIT_VM(6);               // retire G(0); leave {G(1), A(0)} in flight
    RAW_BARRIER();            // all waves' G(0) landed
    CVT(0);                   // RAW[0] -> BF[0]

    // -------- main loop --------
    // vmcnt FIFO at iter kt (steady): A(kt)4, G(kt+1)2 | A(kt+1)4, G(kt+2)2
#pragma unroll
    for (int kt = 0; kt < NKT; ++kt) {
        if (kt + 1 < NKT) {
            if ((kt & 1) == 0) LOAD_A(kt + 1, afB);
            else               LOAD_A(kt + 1, afA);
        }
        if (kt + 2 < NKT) STAGE(kt + 2);
        if      (kt + 2 < NKT) WAIT_VM(6);   // retire {A(kt), G(kt+1)}
        else if (kt + 1 < NKT) WAIT_VM(4);   // tail: no G(kt+2) issued
        else                   WAIT_VM(0);   // last iter: drain
        WAIT_LGKM();                         // CVT(kt) ds ops retired (all waves)
        RAW_BARRIER();                       // BF[kt&1] + RAW[(kt+1)%3] visible
        if ((kt & 1) == 0) MFMA_STEP(kt, afA);
        else               MFMA_STEP(kt, afB);
        if (kt + 1 < NKT) CVT(kt + 1);
    }

    // -------- epilogue: out = 2*(acc + bias) --------
    const int orow = m0 + wv*64 + g*4;     // + mi*16 + r
    float bv[4][4];
#pragma unroll
    for (int mi = 0; mi < 4; ++mi)
#pragma unroll
        for (int r = 0; r < 4; ++r)
            bv[mi][r] = bias[orow + mi*16 + r];

    float* outB = out + (size_t)bb * ((size_t)COUT * TT);
#pragma unroll
    for (int mi = 0; mi < 4; ++mi) {
#pragma unroll
        for (int ni = 0; ni < 4; ++ni) {
            const int t = t0 + ni*16 + l15;
#pragma unroll
            for (int r = 0; r < 4; ++r) {
                const int o = orow + mi*16 + r;
                outB[(size_t)o * TT + t] = 2.0f * (acc[mi][ni][r] + bv[mi][r]);
            }
        }
    }
}

extern "C" void kernel_launch(void* const* d_in, const int* in_sizes, int n_in,
                              void* d_out, int out_size, void* d_ws, size_t ws_size,
                              hipStream_t stream)
{
    const float* pre  = (const float*)d_in[0];   // [16, 512, 4096] fp32
    const float* Wp   = (const float*)d_in[1];   // [512, 512] fp32
    const float* bias = (const float*)d_in[2];   // [512] fp32
    float* out = (float*)d_out;                  // [16, 512, 4096] fp32

    const size_t wb_bytes = (size_t)COUT * CIN * sizeof(ushort);   // 512 KiB

    const dim3 grid(BATCH * 2 * 64);   // 16 b x 2 m-tiles x 64 t-tiles = 2048
    const dim3 block(256);

    if (ws_size >= wb_bytes) {
        ushort* Wb = (ushort*)d_ws;
        hipLaunchKernelGGL(wconv, dim3(256), dim3(256), 0, stream, Wp, Wb);
        hipLaunchKernelGGL((conv2x1_gemm<true>), grid, block, 0, stream,
                           pre, Wp, Wb, bias, out);
    } else {
        hipLaunchKernelGGL((conv2x1_gemm<false>), grid, block, 0, stream,
                           pre, Wp, (const ushort*)nullptr, bias, out);
    }
}